// Round 4
// baseline (138.444 us; speedup 1.0000x reference)
//
#include <hip/hip_runtime.h>

typedef _Float16 f16;
typedef f16 f16x8 __attribute__((ext_vector_type(8)));
typedef float f32x16 __attribute__((ext_vector_type(16)));
typedef float f32x4v __attribute__((ext_vector_type(4)));

#define IMG_H 1024
#define IMG_W 1024
#define CIN 64
#define COUT_ 64
#define NBLK 32
#define NACT 512
#define EPS_ 1e-3f

#define WT_ELEMS (36 * 2 * 64 * 8)   // 36864 f16 B-fragments
#define WT_WGS   144                 // 144*256 == WT_ELEMS
#define FLAGS_OFF (WT_ELEMS * 2)

// B-fragments for mfma_f32_32x32x16_f16 (verified in R2):
//   kstep ks = tap*4 + q ; lane l elem j: k = (l>>5)*8+j -> cin = q*16 + (l>>5)*8 + j
//   col = l&31 -> cout = ch*32 + (l&31)
__global__ void prep_k(const float* __restrict__ w, const int* __restrict__ abi,
                       f16* __restrict__ wt, int* __restrict__ flags) {
    int wg = blockIdx.x;
    if (wg == WT_WGS) {
        int tid = threadIdx.x;
        for (int i = tid; i < NBLK * NBLK; i += 256) flags[i] = 0;
        __syncthreads();
        for (int t = tid; t < NACT; t += 256) {
            int bi = abi[3 * t + 1];
            int bj = abi[3 * t + 2];
            flags[bi * NBLK + bj] = 1;
        }
        return;
    }
    int t = wg * 256 + threadIdx.x;
    int j  = t & 7;
    int l  = (t >> 3) & 63;
    int ch = (t >> 9) & 1;
    int ks = t >> 10;                 // 0..35
    int tap = ks >> 2, q = ks & 3;
    int ky = tap / 3, kx = tap % 3;
    int cin  = q * 16 + ((l >> 5) << 3) + j;
    int cout = ch * 32 + (l & 31);
    wt[t] = (f16)w[((ky * 3 + kx) * CIN + cin) * COUT_ + cout];
}

__launch_bounds__(256, 3)
__global__ void fused_k(const float* __restrict__ inp,
                        const f16*  __restrict__ wt,
                        const float* __restrict__ cb,
                        const float* __restrict__ gamma,
                        const float* __restrict__ beta,
                        const float* __restrict__ rmean,
                        const float* __restrict__ rvar,
                        const int*  __restrict__ abi,
                        const int*  __restrict__ flags,
                        float* __restrict__ out) {
    // patch: 10 rows x 34 cols x 8 channel-groups of 16B (f16x8), XOR-swizzled
    __shared__ uint4 lds[10 * 34 * 8];   // 43520 B -> 3 wg/CU

    const int wg  = blockIdx.x;
    const int tid = threadIdx.x;
    const int r3  = wg % 3;
    const int z3  = wg / 3;

    if (r3 == 1) {
        // ---- zero-duty: one wg per (bi,bj); zero if inactive ----
        int b = z3;
        if (flags[b]) return;
        int bi = b >> 5, bj = b & 31;
        f32x4v z = {0.f, 0.f, 0.f, 0.f};
        f32x4v* base = (f32x4v*)(out + ((size_t)(bi * 32) * IMG_W + bj * 32) * COUT_);
        for (int it = tid; it < 32 * 512; it += 256) {
            int r  = it >> 9;
            int c4 = it & 511;
            __builtin_nontemporal_store(z, &base[(size_t)r * (IMG_W * COUT_ / 4) + c4]);
        }
        return;
    }

    // ---- conv duty: one wg per quarter-block (8 rows x 32 cols) ----
    const int ci = 2 * z3 + (r3 >> 1);
    const int ab = ci >> 2, qt = ci & 3;
    const int bi = abi[3 * ab + 1];
    const int bj = abi[3 * ab + 2];
    const int lane = tid & 63;
    const int wv   = tid >> 6;

    // stage 10x34x64 patch (fp32 -> f16, swizzled channel groups)
    const int r0 = bi * 32 + qt * 8 - 1;
    const int c0 = bj * 32 - 1;
    for (int task = tid; task < 10 * 34 * 8; task += 256) {
        int g  = task & 7;
        int p  = task >> 3;
        int dr = p / 34;
        int dc = p - dr * 34;
        int row = r0 + dr, col = c0 + dc;
        float4 a = make_float4(0.f, 0.f, 0.f, 0.f), b = a;
        if ((unsigned)row < IMG_H && (unsigned)col < IMG_W) {
            const float4* src = (const float4*)(inp + (((size_t)row * IMG_W + col) * CIN + g * 8));
            a = src[0]; b = src[1];
        }
        f16x8 v;
        v[0] = (f16)a.x; v[1] = (f16)a.y; v[2] = (f16)a.z; v[3] = (f16)a.w;
        v[4] = (f16)b.x; v[5] = (f16)b.y; v[6] = (f16)b.z; v[7] = (f16)b.w;
        lds[(p << 3) + (g ^ (dc & 7))] = __builtin_bit_cast(uint4, v);
    }

    // per-wave B-fragments: wave = (row-group rg, cout-half chh)
    const int rg  = wv & 1;
    const int chh = wv >> 1;
    f16x8 wf[36];
    const uint4* wt4 = (const uint4*)wt;
    #pragma unroll
    for (int ks = 0; ks < 36; ++ks)
        wf[ks] = __builtin_bit_cast(f16x8, wt4[(ks * 2 + chh) * 64 + lane]);

    const int co = chh * 32 + (lane & 31);
    const float sc = gamma[co] * rsqrtf(rvar[co] + EPS_);
    const float sh = cb[co] * sc + beta[co] - rmean[co] * sc;

    __syncthreads();

    const int px = lane & 31;      // A row = output pixel column
    const int hi = lane >> 5;      // k sub-group
    float* outb = out + (((size_t)(bi * 32 + qt * 8) * IMG_W) + bj * 32) * COUT_;

    for (int yr = 0; yr < 4; ++yr) {
        const int R = rg * 4 + yr;
        f32x16 accA = {0.f,0.f,0.f,0.f,0.f,0.f,0.f,0.f,0.f,0.f,0.f,0.f,0.f,0.f,0.f,0.f};
        f32x16 accB = {0.f,0.f,0.f,0.f,0.f,0.f,0.f,0.f,0.f,0.f,0.f,0.f,0.f,0.f,0.f,0.f};
        #pragma unroll
        for (int ks = 0; ks < 36; ++ks) {
            const int tap = ks >> 2, q = ks & 3;
            const int ky = tap / 3, kx = tap % 3;
            const int dr = R + ky;
            const int dc = px + kx;
            const int slot = (q * 2 + hi) ^ (dc & 7);
            uint4 a = lds[((dr * 34 + dc) << 3) + slot];
            if (ks & 1)
                accB = __builtin_amdgcn_mfma_f32_32x32x16_f16(__builtin_bit_cast(f16x8, a), wf[ks], accB, 0, 0, 0);
            else
                accA = __builtin_amdgcn_mfma_f32_32x32x16_f16(__builtin_bit_cast(f16x8, a), wf[ks], accA, 0, 0, 0);
        }
        #pragma unroll
        for (int r = 0; r < 16; ++r) {
            const int pxo = (r & 3) + 8 * (r >> 2) + 4 * hi;
            float v = fmaxf((accA[r] + accB[r]) * sc + sh, 0.f);
            __builtin_nontemporal_store(v, &outb[((size_t)R * IMG_W + pxo) * COUT_ + co]);
        }
    }
}

extern "C" void kernel_launch(void* const* d_in, const int* in_sizes, int n_in,
                              void* d_out, int out_size, void* d_ws, size_t ws_size,
                              hipStream_t stream) {
    const float* inp   = (const float*)d_in[0];
    const float* convw = (const float*)d_in[1];
    const float* convb = (const float*)d_in[2];
    const float* gamma = (const float*)d_in[3];
    const float* beta  = (const float*)d_in[4];
    const float* rmean = (const float*)d_in[5];
    const float* rvar  = (const float*)d_in[6];
    const int*   abi   = (const int*)d_in[7];
    float* out = (float*)d_out;

    f16* wt    = (f16*)d_ws;
    int* flags = (int*)((char*)d_ws + FLAGS_OFF);

    hipLaunchKernelGGL(prep_k, dim3(WT_WGS + 1), dim3(256), 0, stream, convw, abi, wt, flags);
    hipLaunchKernelGGL(fused_k, dim3(3 * NBLK * NBLK), dim3(256), 0, stream,
                       inp, wt, convb, gamma, beta, rmean, rvar, abi, flags, out);
}